// Round 4
// baseline (33.457 us; speedup 1.0000x reference)
//
#include <hip/hip_runtime.h>

// NodeCycleFeatures: B=2048 graphs, N=64, A = E[...,1] symmetric 0/1, zero diag.
// 4 waves per batch (256-thread block). Lane i owns row i (as u32 lo/hi mask);
// wave w owns the k/j-subrange [16w, 16w+16) of the O(N^2) popcount loops.
// Inner loops use v_readlane broadcasts (no LDS on the critical path):
//   k2[i][k] = popcount(row_i & row_k), kept as 6 bit-planes ->
//   k3[i][j] = sum_t 2^t * popcount(plane_t & row_j).  Integer-exact in fp32.

constexpr int BATCH = 2048;
constexpr int NN = 64;

__device__ __forceinline__ unsigned rdl(unsigned v, int l) {
  return (unsigned)__builtin_amdgcn_readlane((int)v, l);
}
__device__ __forceinline__ float rdlf(float v, int l) {
  return __uint_as_float((unsigned)__builtin_amdgcn_readlane((int)__float_as_uint(v), l));
}

__global__ __launch_bounds__(256, 8) void node_cycle_kernel(
    const float2* __restrict__ E2,   // [B,N,N] of (1-A, A)
    const float* __restrict__ nmask, // [B,N]
    float* __restrict__ out)         // x: [B,N,3] then y: [B,4]
{
  const int b = blockIdx.x;
  const int tid = threadIdx.x;
  const int lane = tid & 63;
  const int w = tid >> 6;            // wave id 0..3
  const int k0 = w * 16;             // this wave's k/j subrange base

  __shared__ unsigned rows_lo[NN], rows_hi[NN];
  __shared__ unsigned ppart[4][6][NN];   // per-wave partial bit-planes (16 bits)
  __shared__ float c3part[4][NN];
  __shared__ float accs[4][7][NN];       // per-wave float partials

  const float2* __restrict__ Eb = E2 + (size_t)b * (NN * NN);

  // ---- Phase 1: wave w ballots rows [16w, 16w+16); distribute via LDS ----
  #pragma unroll
  for (int i = 0; i < 16; ++i) {
    const int r = k0 + i;
    const float v = Eb[r * NN + lane].y;        // A[b, r, lane]
    const unsigned long long m = __ballot(v > 0.5f);
    if (lane == r) { rows_lo[r] = (unsigned)m; rows_hi[r] = (unsigned)(m >> 32); }
  }
  __syncthreads();

  const unsigned mlo = rows_lo[lane];            // lane i holds row i
  const unsigned mhi = rows_hi[lane];
  const float di = (float)(__popc(mlo) + __popc(mhi));
  const unsigned long long myrow = ((unsigned long long)mhi << 32) | mlo;
  const unsigned nb = (unsigned)(myrow >> k0) & 0xffffu; // bit q = A[lane][k0+q]

  // ---- Phase 2: k2[lane][k], k in subrange; planes + diag4/c3/t3 partials ----
  unsigned pp0=0,pp1=0,pp2=0,pp3=0,pp4=0,pp5=0;
  unsigned pk[4] = {0u,0u,0u,0u};                // packed k2 bytes for phase 3
  float diag4 = 0.f, c3 = 0.f, t3p = 0.f;
  #pragma unroll
  for (int q = 0; q < 16; ++q) {
    const int k = k0 + q;
    const unsigned rl = rdl(mlo, k);             // row k (uniform, SGPR)
    const unsigned rh = rdl(mhi, k);
    const unsigned p = (unsigned)__popc(rl & mlo) + (unsigned)__popc(rh & mhi);
    pp0 |= ((p      ) & 1u) << q;
    pp1 |= ((p >> 1) & 1u) << q;
    pp2 |= ((p >> 2) & 1u) << q;
    pp3 |= ((p >> 3) & 1u) << q;
    pp4 |= ((p >> 4) & 1u) << q;
    pp5 |= ((p >> 5) & 1u) << q;
    pk[q >> 2] |= p << (8 * (q & 3));            // static index under unroll
    const float pf = (float)p;
    diag4 = fmaf(pf, pf, diag4);
    const float selpf = ((nb >> q) & 1u) ? pf : 0.f;
    c3 += selpf;
    t3p = fmaf(selpf, pf, t3p);
  }
  ppart[w][0][lane]=pp0; ppart[w][1][lane]=pp1; ppart[w][2][lane]=pp2;
  ppart[w][3][lane]=pp3; ppart[w][4][lane]=pp4; ppart[w][5][lane]=pp5;
  c3part[w][lane] = c3;
  accs[w][0][lane] = diag4;
  accs[w][1][lane] = t3p;
  __syncthreads();

  // ---- Merge (redundant in each wave): full bit-planes + full c3 ----
  unsigned pl_lo[6], pl_hi[6];
  #pragma unroll
  for (int t = 0; t < 6; ++t) {
    pl_lo[t] = ppart[0][t][lane] | (ppart[1][t][lane] << 16);
    pl_hi[t] = ppart[2][t][lane] | (ppart[3][t][lane] << 16);
  }
  const float c3f = c3part[0][lane] + c3part[1][lane]
                  + c3part[2][lane] + c3part[3][lane];

  // ---- Phase 3: k3[lane][j] via bit-plane popcounts; readlane broadcasts ----
  float t1p=0.f, t8p=0.f, diag5=0.f, Ad=0.f, Atri=0.f;
  #pragma unroll
  for (int q = 0; q < 16; ++q) {
    const int j = k0 + q;
    const unsigned rl = rdl(mlo, j);             // row j (uniform, SGPR)
    const unsigned rh = rdl(mhi, j);
    unsigned s = (unsigned)__popc(pl_lo[0] & rl) + (unsigned)__popc(pl_hi[0] & rh);
    s += ((unsigned)__popc(pl_lo[1] & rl) + (unsigned)__popc(pl_hi[1] & rh)) << 1;
    s += ((unsigned)__popc(pl_lo[2] & rl) + (unsigned)__popc(pl_hi[2] & rh)) << 2;
    s += ((unsigned)__popc(pl_lo[3] & rl) + (unsigned)__popc(pl_hi[3] & rh)) << 3;
    s += ((unsigned)__popc(pl_lo[4] & rl) + (unsigned)__popc(pl_hi[4] & rh)) << 4;
    s += ((unsigned)__popc(pl_lo[5] & rl) + (unsigned)__popc(pl_hi[5] & rh)) << 5;
    const unsigned pj = (pk[q >> 2] >> (8 * (q & 3))) & 0xffu; // k2[lane][j]
    const float sf = (float)s;
    t1p = fmaf(sf, sf, t1p);                     // -> trace(k6)
    t8p += sf;                                   // -> sum(k3)
    diag5 = fmaf((float)pj, sf, diag5);          // -> diag(A^5)
    const float dj = rdlf(di, j);                // deg(j)  (uniform)
    const float cj = rdlf(c3f, j);               // c3(j)   (uniform)
    const unsigned bit = (nb >> q) & 1u;
    Ad   += bit ? dj : 0.f;                      // -> (A@d)[lane]
    Atri += bit ? cj : 0.f;                      // -> (A@c3)[lane]
  }
  accs[w][2][lane]=t1p; accs[w][3][lane]=t8p; accs[w][4][lane]=diag5;
  accs[w][5][lane]=Ad;  accs[w][6][lane]=Atri;
  __syncthreads();

  // ---- Final: wave 0 merges partials, computes node/graph outputs ----
  if (w == 0) {
    float f[7];
    #pragma unroll
    for (int q2 = 0; q2 < 7; ++q2)
      f[q2] = accs[0][q2][lane] + accs[1][q2][lane]
            + accs[2][q2][lane] + accs[3][q2][lane];
    const float diag4F=f[0], t3F=f[1], t1F=f[2], t8F=f[3], d5F=f[4], AdF=f[5], AtF=f[6];

    const float c4 = diag4F - di * (di - 1.f) - AdF;
    const float c5 = d5F - 2.f * c3f * di - AtF + c3f;
    const float c6p = t1F
              - 3.f * (c3f * c3f)
              + 9.f * t3F
              - 6.f * (di * diag4F)
              + 6.f * diag4F
              - 4.f * c3f
              + 4.f * (di * di * di)
              + 3.f * t8F
              - 12.f * (di * di)
              + 4.f * di;

    float sc3 = c3f, sc4 = c4, sc5 = c5, sc6 = c6p;
    #pragma unroll
    for (int off = 32; off > 0; off >>= 1) {
      sc3 += __shfl_xor(sc3, off);
      sc4 += __shfl_xor(sc4, off);
      sc5 += __shfl_xor(sc5, off);
      sc6 += __shfl_xor(sc6, off);
    }

    const float m = nmask[b * NN + lane];
    float* xo = out + ((size_t)b * NN + lane) * 3;
    xo[0] = fminf(c3f * 0.5f * m * 0.1f, 1.f);
    xo[1] = fminf(c4 * 0.5f * m * 0.1f, 1.f);
    xo[2] = fminf(c5 * 0.5f * m * 0.1f, 1.f);

    if (lane == 0) {
      float4 y;
      y.x = fminf(sc3 * (1.f / 6.f)  * 0.1f, 1.f);
      y.y = fminf(sc4 * (1.f / 8.f)  * 0.1f, 1.f);
      y.z = fminf(sc5 * (1.f / 10.f) * 0.1f, 1.f);
      y.w = fminf(sc6 * (1.f / 12.f) * 0.1f, 1.f);
      *reinterpret_cast<float4*>(out + (size_t)BATCH * NN * 3 + b * 4) = y;
    }
  }
}

extern "C" void kernel_launch(void* const* d_in, const int* in_sizes, int n_in,
                              void* d_out, int out_size, void* d_ws, size_t ws_size,
                              hipStream_t stream) {
  const float2* E2 = reinterpret_cast<const float2*>(d_in[0]);
  const float* nmask = reinterpret_cast<const float*>(d_in[1]);
  float* out = reinterpret_cast<float*>(d_out);
  node_cycle_kernel<<<BATCH, 256, 0, stream>>>(E2, nmask, out);
}

// Round 5
// 26.609 us; speedup vs baseline: 1.2574x; 1.2574x over previous
//
#include <hip/hip_runtime.h>

// NodeCycleFeatures: B=2048 graphs, N=64, A = E[...,1] symmetric 0/1, zero diag.
// 4 waves per block-batch; 2 batches per block, software-pipelined:
// batch m+1's A values are prefetched into registers during batch m's compute.
// Lane i owns row i as a 64-bit mask. k2[i][k] = popcount(row_i & row_k),
// kept as 6 bit-planes -> k3[i][j] = sum_t 2^t popcount(plane_t & row_j).
// Inner-loop broadcasts via one uniform ds_read_b128 (jinfo = {row_lo, row_hi,
// deg, c3}). All quantities integer-exact in fp32.

constexpr int BATCH = 2048;
constexpr int NN = 64;
constexpr int NB = 2;               // batches per block (pipelined)
constexpr int GRID = BATCH / NB;

union UF { unsigned u; float f; };

__global__ __launch_bounds__(256, 4) void node_cycle_kernel(
    const float* __restrict__ Ef,    // [B,N,N,2] floats; A = element .y
    const float* __restrict__ nmask, // [B,N]
    float* __restrict__ out)         // x: [B,N,3] then y: [B,4]
{
  const int tid = threadIdx.x;
  const int lane = tid & 63;
  const int w = tid >> 6;            // wave id 0..3
  const int k0 = w * 16;             // this wave's k/j subrange base
  const int b0 = blockIdx.x * NB;

  __shared__ uint4 jinfo[NN];                  // {row_lo, row_hi, deg_f, c3_f}
  __shared__ unsigned ppart[4][6][NN];         // partial bit-planes (16 bits)
  __shared__ float c3part[4][NN];
  __shared__ float accs[4][7][NN];             // per-wave float partials

  // ---- Prologue: prefetch batch b0's A values (only the .y floats) ----
  float pref[16];
  #pragma unroll
  for (int q = 0; q < 16; ++q)
    pref[q] = Ef[(((size_t)b0 * (NN * NN)) + (k0 + q) * NN + lane) * 2 + 1];

  for (int m = 0; m < NB; ++m) {
    const int b = b0 + m;

    // ---- Phase 1: ballot row masks from prefetched registers ----
    #pragma unroll
    for (int q = 0; q < 16; ++q) {
      const int r = k0 + q;
      const unsigned long long msk = __ballot(pref[q] > 0.5f);
      if (lane == r) {
        jinfo[r].x = (unsigned)msk;
        jinfo[r].y = (unsigned)(msk >> 32);
      }
    }
    // Issue next batch's loads NOW; they stay in flight across phases 2/3.
    if (m + 1 < NB) {
      #pragma unroll
      for (int q = 0; q < 16; ++q)
        pref[q] = Ef[(((size_t)(b + 1) * (NN * NN)) + (k0 + q) * NN + lane) * 2 + 1];
    }
    __syncthreads();                            // S1

    const unsigned mlo = jinfo[lane].x;         // lane i holds row i
    const unsigned mhi = jinfo[lane].y;
    const float di = (float)(__popc(mlo) + __popc(mhi));
    if (w == 0) { UF d; d.f = di; jinfo[lane].z = d.u; }
    const unsigned long long myrow = ((unsigned long long)mhi << 32) | mlo;
    const unsigned nb16 = (unsigned)(myrow >> k0) & 0xffffu; // bit q = A[lane][k0+q]

    // ---- Phase 2: k2[lane][k] (k in subrange); planes + diag4/c3/t3 ----
    unsigned pp0=0,pp1=0,pp2=0,pp3=0,pp4=0,pp5=0;
    unsigned pk[4] = {0u,0u,0u,0u};
    float diag4 = 0.f, c3 = 0.f, t3p = 0.f;
    #pragma unroll
    for (int q = 0; q < 16; ++q) {
      const uint4 ji = jinfo[k0 + q];           // uniform broadcast b128
      const unsigned p = (unsigned)__popc(ji.x & mlo) + (unsigned)__popc(ji.y & mhi);
      pp0 |= ((p      ) & 1u) << q;
      pp1 |= ((p >> 1) & 1u) << q;
      pp2 |= ((p >> 2) & 1u) << q;
      pp3 |= ((p >> 3) & 1u) << q;
      pp4 |= ((p >> 4) & 1u) << q;
      pp5 |= ((p >> 5) & 1u) << q;
      pk[q >> 2] |= p << (8 * (q & 3));         // static index under unroll
      const float pf = (float)p;
      diag4 = fmaf(pf, pf, diag4);
      const float selpf = ((nb16 >> q) & 1u) ? pf : 0.f;
      c3 += selpf;
      t3p = fmaf(selpf, pf, t3p);
    }
    ppart[w][0][lane]=pp0; ppart[w][1][lane]=pp1; ppart[w][2][lane]=pp2;
    ppart[w][3][lane]=pp3; ppart[w][4][lane]=pp4; ppart[w][5][lane]=pp5;
    c3part[w][lane] = c3;
    accs[w][0][lane] = diag4;
    accs[w][1][lane] = t3p;
    __syncthreads();                            // S2

    // ---- Merge: full bit-planes + full c3 ----
    unsigned pl_lo[6], pl_hi[6];
    #pragma unroll
    for (int t = 0; t < 6; ++t) {
      pl_lo[t] = ppart[0][t][lane] | (ppart[1][t][lane] << 16);
      pl_hi[t] = ppart[2][t][lane] | (ppart[3][t][lane] << 16);
    }
    const float c3f = c3part[0][lane] + c3part[1][lane]
                    + c3part[2][lane] + c3part[3][lane];
    if (w == 0) { UF u; u.f = c3f; jinfo[lane].w = u.u; }
    __syncthreads();                            // S3

    // ---- Phase 3: k3[lane][j] via bit-plane popcounts ----
    float t1p=0.f, t8p=0.f, diag5=0.f, Ad=0.f, Atri=0.f;
    #pragma unroll
    for (int q = 0; q < 16; ++q) {
      const uint4 ji = jinfo[k0 + q];           // uniform broadcast b128
      unsigned s = (unsigned)__popc(pl_lo[0] & ji.x) + (unsigned)__popc(pl_hi[0] & ji.y);
      s += ((unsigned)__popc(pl_lo[1] & ji.x) + (unsigned)__popc(pl_hi[1] & ji.y)) << 1;
      s += ((unsigned)__popc(pl_lo[2] & ji.x) + (unsigned)__popc(pl_hi[2] & ji.y)) << 2;
      s += ((unsigned)__popc(pl_lo[3] & ji.x) + (unsigned)__popc(pl_hi[3] & ji.y)) << 3;
      s += ((unsigned)__popc(pl_lo[4] & ji.x) + (unsigned)__popc(pl_hi[4] & ji.y)) << 4;
      s += ((unsigned)__popc(pl_lo[5] & ji.x) + (unsigned)__popc(pl_hi[5] & ji.y)) << 5;
      const unsigned pj = (pk[q >> 2] >> (8 * (q & 3))) & 0xffu; // k2[lane][j]
      const float sf = (float)s;
      t1p = fmaf(sf, sf, t1p);                  // -> trace(k6)
      t8p += sf;                                // -> sum(k3)
      diag5 = fmaf((float)pj, sf, diag5);       // -> diag(A^5)
      UF dj; dj.u = ji.z;                       // deg(j)
      UF cj; cj.u = ji.w;                       // c3(j)
      const unsigned bit = (nb16 >> q) & 1u;
      Ad   += bit ? dj.f : 0.f;                 // -> (A@d)[lane]
      Atri += bit ? cj.f : 0.f;                 // -> (A@c3)[lane]
    }
    accs[w][2][lane]=t1p; accs[w][3][lane]=t8p; accs[w][4][lane]=diag5;
    accs[w][5][lane]=Ad;  accs[w][6][lane]=Atri;
    __syncthreads();                            // S4

    // ---- Final: wave 0 merges partials, computes outputs ----
    // (w1-3 may race ahead into next phase 1; they only write jinfo.x/.y,
    //  which this final phase never reads. Next S1 re-orders everything.)
    if (w == 0) {
      float f[7];
      #pragma unroll
      for (int q2 = 0; q2 < 7; ++q2)
        f[q2] = accs[0][q2][lane] + accs[1][q2][lane]
              + accs[2][q2][lane] + accs[3][q2][lane];
      const float diag4F=f[0], t3F=f[1], t1F=f[2], t8F=f[3], d5F=f[4], AdF=f[5], AtF=f[6];

      const float c4 = diag4F - di * (di - 1.f) - AdF;
      const float c5 = d5F - 2.f * c3f * di - AtF + c3f;
      const float c6p = t1F
                - 3.f * (c3f * c3f)
                + 9.f * t3F
                - 6.f * (di * diag4F)
                + 6.f * diag4F
                - 4.f * c3f
                + 4.f * (di * di * di)
                + 3.f * t8F
                - 12.f * (di * di)
                + 4.f * di;

      float sc3 = c3f, sc4 = c4, sc5 = c5, sc6 = c6p;
      #pragma unroll
      for (int off = 32; off > 0; off >>= 1) {
        sc3 += __shfl_xor(sc3, off);
        sc4 += __shfl_xor(sc4, off);
        sc5 += __shfl_xor(sc5, off);
        sc6 += __shfl_xor(sc6, off);
      }

      const float msk = nmask[b * NN + lane];
      float* xo = out + ((size_t)b * NN + lane) * 3;
      xo[0] = fminf(c3f * 0.5f * msk * 0.1f, 1.f);
      xo[1] = fminf(c4 * 0.5f * msk * 0.1f, 1.f);
      xo[2] = fminf(c5 * 0.5f * msk * 0.1f, 1.f);

      if (lane == 0) {
        float4 y;
        y.x = fminf(sc3 * (1.f / 6.f)  * 0.1f, 1.f);
        y.y = fminf(sc4 * (1.f / 8.f)  * 0.1f, 1.f);
        y.z = fminf(sc5 * (1.f / 10.f) * 0.1f, 1.f);
        y.w = fminf(sc6 * (1.f / 12.f) * 0.1f, 1.f);
        *reinterpret_cast<float4*>(out + (size_t)BATCH * NN * 3 + b * 4) = y;
      }
    }
  }
}

extern "C" void kernel_launch(void* const* d_in, const int* in_sizes, int n_in,
                              void* d_out, int out_size, void* d_ws, size_t ws_size,
                              hipStream_t stream) {
  const float* Ef = reinterpret_cast<const float*>(d_in[0]);
  const float* nmask = reinterpret_cast<const float*>(d_in[1]);
  float* out = reinterpret_cast<float*>(d_out);
  node_cycle_kernel<<<GRID, 256, 0, stream>>>(Ef, nmask, out);
}